// Round 2
// baseline (475.032 us; speedup 1.0000x reference)
//
#include <hip/hip_runtime.h>

// N=65536, D_OUT=128, D_LAT=64, D_Z=64. Pure streaming multi-reduction.
constexpr int N_ROWS  = 65536;
constexpr int BLOCKS  = 2048;               // 8 blocks/CU -> up to 32 waves/CU
constexpr int THREADS = 256;
constexpr int T_TOT   = BLOCKS * THREADS;   // 524288, divisible by 16

constexpr int R_IT = (N_ROWS * 128 / 4) / T_TOT;  // 4 (exact)
constexpr int K_IT = (N_ROWS *  64 / 4) / T_TOT;  // 2 (exact)
constexpr int Z_IT = K_IT;                        // 2

// ws layout (floats): [0]=recon_sum, [1]=kl_sum, [2+st*64+col] col stats (5*64),
// [324] = ticket counter (as unsigned). memset covers [0..511].

__device__ __forceinline__ float agent_load(const float* p) {
    return __hip_atomic_load(p, __ATOMIC_RELAXED, __HIP_MEMORY_SCOPE_AGENT);
}

__global__ __launch_bounds__(THREADS, 4) void vde_fused(
    const float4* __restrict__ target,
    const float4* __restrict__ output,
    const float4* __restrict__ mean,
    const float4* __restrict__ logvar,
    const float4* __restrict__ zt,
    const float4* __restrict__ ztau,
    float* __restrict__ ws,
    float* __restrict__ out)
{
    const int tid  = blockIdx.x * THREADS + threadIdx.x;
    const int lane = threadIdx.x & 63;
    const int wave = threadIdx.x >> 6;

    // ---- issue all loads as early as possible (straight-line, full unroll) ----
    float4 ro[R_IT], rt[R_IT];
    #pragma unroll
    for (int it = 0; it < R_IT; ++it) {
        ro[it] = output[tid + it * T_TOT];
        rt[it] = target[tid + it * T_TOT];
    }
    float4 klv[K_IT], km[K_IT];
    #pragma unroll
    for (int it = 0; it < K_IT; ++it) {
        klv[it] = logvar[tid + it * T_TOT];
        km[it]  = mean[tid + it * T_TOT];
    }
    float4 za[Z_IT], zb[Z_IT];
    #pragma unroll
    for (int it = 0; it < Z_IT; ++it) {
        za[it] = zt[tid + it * T_TOT];
        zb[it] = ztau[tid + it * T_TOT];
    }

    // ---- reconstruction MSE partial ----
    float recon = 0.f;
    #pragma unroll
    for (int it = 0; it < R_IT; ++it) {
        float dx = ro[it].x - rt[it].x, dy = ro[it].y - rt[it].y;
        float dz = ro[it].z - rt[it].z, dw = ro[it].w - rt[it].w;
        recon += dx * dx + dy * dy + dz * dz + dw * dw;
    }

    // ---- KL partial: sum (lv - e^lv - m^2 + 1) ----
    float kls = 0.f;
    #pragma unroll
    for (int it = 0; it < K_IT; ++it) {
        float4 lv = klv[it], m = km[it];
        kls += (lv.x - __expf(lv.x) - m.x * m.x + 1.f)
             + (lv.y - __expf(lv.y) - m.y * m.y + 1.f)
             + (lv.z - __expf(lv.z) - m.z * m.z + 1.f)
             + (lv.w - __expf(lv.w) - m.w * m.w + 1.f);
    }

    // ---- per-column z statistics (thread's float4 index % 16 is fixed) ----
    float s_t[4] = {0,0,0,0}, s_t2[4] = {0,0,0,0};
    float s_a[4] = {0,0,0,0}, s_a2[4] = {0,0,0,0}, s_c[4] = {0,0,0,0};
    #pragma unroll
    for (int it = 0; it < Z_IT; ++it) {
        const float ax[4] = {za[it].x, za[it].y, za[it].z, za[it].w};
        const float bx[4] = {zb[it].x, zb[it].y, zb[it].z, zb[it].w};
        #pragma unroll
        for (int e = 0; e < 4; ++e) {
            s_t[e]  += ax[e];        s_a[e]  += bx[e];
            s_t2[e] += ax[e]*ax[e];  s_a2[e] += bx[e]*bx[e];
            s_c[e]  += ax[e]*bx[e];
        }
    }

    // ---- scalar reduction: wave shuffle, then across-wave via LDS ----
    #pragma unroll
    for (int m = 32; m >= 1; m >>= 1) {
        recon += __shfl_xor(recon, m);
        kls   += __shfl_xor(kls, m);
    }
    __shared__ float ssc[4][2];
    if (lane == 0) { ssc[wave][0] = recon; ssc[wave][1] = kls; }

    // ---- per-column-group reduction: lanes {l, l^16, l^32, l^48} share group ----
    float vals[20];
    #pragma unroll
    for (int e = 0; e < 4; ++e) {
        vals[e*5+0] = s_t[e];  vals[e*5+1] = s_a[e];
        vals[e*5+2] = s_t2[e]; vals[e*5+3] = s_a2[e];
        vals[e*5+4] = s_c[e];
    }
    #pragma unroll
    for (int v = 0; v < 20; ++v) {
        vals[v] += __shfl_xor(vals[v], 16);
        vals[v] += __shfl_xor(vals[v], 32);
    }
    __shared__ float sred[4][16][20];
    if (lane < 16) {
        #pragma unroll
        for (int v = 0; v < 20; ++v) sred[wave][lane][v] = vals[v];
    }
    __syncthreads();

    if (threadIdx.x == 0) {
        atomicAdd(&ws[0], ssc[0][0] + ssc[1][0] + ssc[2][0] + ssc[3][0]);
        atomicAdd(&ws[1], ssc[0][1] + ssc[1][1] + ssc[2][1] + ssc[3][1]);
    }
    for (int i = threadIdx.x; i < 320; i += THREADS) {
        const int g = i / 20, v = i % 20;
        const float s = sred[0][g][v] + sred[1][g][v] + sred[2][g][v] + sred[3][g][v];
        const int e = v / 5, st = v % 5;
        atomicAdd(&ws[2 + st * 64 + (g * 4 + e)], s);
    }

    // ---- last-block-done ticket -> fused finalize ----
    __shared__ unsigned s_last;
    __threadfence();                         // order our atomics before the ticket
    if (threadIdx.x == 0) {
        unsigned* ticket = (unsigned*)&ws[324];
        s_last = (atomicAdd(ticket, 1u) == (unsigned)(BLOCKS - 1));
    }
    __syncthreads();
    if (!s_last) return;

    __threadfence();                         // acquire: see all blocks' sums
    if (threadIdx.x < 64) {
        const int j = threadIdx.x;
        const float Nf = (float)N_ROWS;
        const float sum_t  = agent_load(&ws[2 + 0*64 + j]);
        const float sum_a  = agent_load(&ws[2 + 1*64 + j]);
        const float sum_t2 = agent_load(&ws[2 + 2*64 + j]);
        const float sum_a2 = agent_load(&ws[2 + 3*64 + j]);
        const float sum_c  = agent_load(&ws[2 + 4*64 + j]);

        const float mu_t = sum_t / Nf, mu_a = sum_a / Nf;
        float diag = sum_c - Nf * mu_t * mu_a;
        const float var_t = (sum_t2 - Nf * mu_t * mu_t) / (Nf - 1.f);
        const float var_a = (sum_a2 - Nf * mu_a * mu_a) / (Nf - 1.f);
        float sp = sqrtf(var_t) * sqrtf(var_a);

        #pragma unroll
        for (int m = 32; m >= 1; m >>= 1) {
            diag += __shfl_xor(diag, m);
            sp   += __shfl_xor(sp, m);
        }
        if (j == 0) {
            const float recon_f = agent_load(&ws[0]) / (Nf * 128.f);
            const float kl_f    = -0.5f * agent_load(&ws[1]) / Nf;
            out[0] = recon_f + kl_f - (diag / Nf) / sp;
        }
    }
}

extern "C" void kernel_launch(void* const* d_in, const int* in_sizes, int n_in,
                              void* d_out, int out_size, void* d_ws, size_t ws_size,
                              hipStream_t stream) {
    const float4* target = (const float4*)d_in[0];
    const float4* output = (const float4*)d_in[1];
    const float4* mean   = (const float4*)d_in[2];
    const float4* logvar = (const float4*)d_in[3];
    const float4* zt     = (const float4*)d_in[4];
    const float4* ztau   = (const float4*)d_in[5];
    float* ws  = (float*)d_ws;
    float* out = (float*)d_out;

    // ws is re-poisoned to 0xAA before every timed launch -> zero accumulators+ticket
    hipMemsetAsync(ws, 0, 512 * sizeof(float), stream);
    vde_fused<<<BLOCKS, THREADS, 0, stream>>>(target, output, mean, logvar, zt, ztau, ws, out);
}

// Round 3
// 160.523 us; speedup vs baseline: 2.9593x; 2.9593x over previous
//
#include <hip/hip_runtime.h>

// N=65536, D_OUT=128, D_LAT=64, D_Z=64. Pure streaming multi-reduction.
// R2 lesson: contended device-scope fp32 atomics cost ~100-150ns each when
// 2048 blocks hit the same address. Fix: 64 accumulator replicas.
constexpr int N_ROWS  = 65536;
constexpr int BLOCKS  = 2048;               // 8 blocks/CU
constexpr int THREADS = 256;
constexpr int T_TOT   = BLOCKS * THREADS;   // 524288, divisible by 16

constexpr int R_IT = (N_ROWS * 128 / 4) / T_TOT;  // 4 (exact)
constexpr int K_IT = (N_ROWS *  64 / 4) / T_TOT;  // 2 (exact)
constexpr int Z_IT = K_IT;                        // 2

constexpr int NVAL = 324;   // [0]=recon, [1]=kl, [2+st*64+col] (5*64)
constexpr int NREP = 64;    // atomic replicas -> contention 2048/64 = 32 per addr

// ws layout (floats):
//   [r*NVAL + v]            r in [0,64): replicated accumulators (memset to 0)
//   [NREP*NVAL + v]         collapsed sums (written by vde_collapse)

__global__ __launch_bounds__(THREADS) void vde_main(
    const float4* __restrict__ target,
    const float4* __restrict__ output,
    const float4* __restrict__ mean,
    const float4* __restrict__ logvar,
    const float4* __restrict__ zt,
    const float4* __restrict__ ztau,
    float* __restrict__ ws)
{
    const int tid  = blockIdx.x * THREADS + threadIdx.x;
    const int lane = threadIdx.x & 63;
    const int wave = threadIdx.x >> 6;
    float* rep = ws + (blockIdx.x & (NREP - 1)) * NVAL;

    // ---- straight-line hoisted loads (16 float4s in flight per thread) ----
    float4 ro[R_IT], rt[R_IT];
    #pragma unroll
    for (int it = 0; it < R_IT; ++it) {
        ro[it] = output[tid + it * T_TOT];
        rt[it] = target[tid + it * T_TOT];
    }
    float4 klv[K_IT], km[K_IT];
    #pragma unroll
    for (int it = 0; it < K_IT; ++it) {
        klv[it] = logvar[tid + it * T_TOT];
        km[it]  = mean[tid + it * T_TOT];
    }
    float4 za[Z_IT], zb[Z_IT];
    #pragma unroll
    for (int it = 0; it < Z_IT; ++it) {
        za[it] = zt[tid + it * T_TOT];
        zb[it] = ztau[tid + it * T_TOT];
    }

    // ---- reconstruction MSE partial ----
    float recon = 0.f;
    #pragma unroll
    for (int it = 0; it < R_IT; ++it) {
        float dx = ro[it].x - rt[it].x, dy = ro[it].y - rt[it].y;
        float dz = ro[it].z - rt[it].z, dw = ro[it].w - rt[it].w;
        recon += dx * dx + dy * dy + dz * dz + dw * dw;
    }

    // ---- KL partial: sum (lv - e^lv - m^2 + 1) ----
    float kls = 0.f;
    #pragma unroll
    for (int it = 0; it < K_IT; ++it) {
        float4 lv = klv[it], m = km[it];
        kls += (lv.x - __expf(lv.x) - m.x * m.x + 1.f)
             + (lv.y - __expf(lv.y) - m.y * m.y + 1.f)
             + (lv.z - __expf(lv.z) - m.z * m.z + 1.f)
             + (lv.w - __expf(lv.w) - m.w * m.w + 1.f);
    }

    // ---- per-column z statistics (thread's float4 index % 16 is fixed) ----
    float s_t[4] = {0,0,0,0}, s_t2[4] = {0,0,0,0};
    float s_a[4] = {0,0,0,0}, s_a2[4] = {0,0,0,0}, s_c[4] = {0,0,0,0};
    #pragma unroll
    for (int it = 0; it < Z_IT; ++it) {
        const float ax[4] = {za[it].x, za[it].y, za[it].z, za[it].w};
        const float bx[4] = {zb[it].x, zb[it].y, zb[it].z, zb[it].w};
        #pragma unroll
        for (int e = 0; e < 4; ++e) {
            s_t[e]  += ax[e];        s_a[e]  += bx[e];
            s_t2[e] += ax[e]*ax[e];  s_a2[e] += bx[e]*bx[e];
            s_c[e]  += ax[e]*bx[e];
        }
    }

    // ---- scalar reduction: wave shuffle, then across-wave via LDS ----
    #pragma unroll
    for (int m = 32; m >= 1; m >>= 1) {
        recon += __shfl_xor(recon, m);
        kls   += __shfl_xor(kls, m);
    }
    __shared__ float ssc[4][2];
    if (lane == 0) { ssc[wave][0] = recon; ssc[wave][1] = kls; }

    // ---- per-column-group reduction: lanes {l, l^16, l^32, l^48} share group ----
    float vals[20];
    #pragma unroll
    for (int e = 0; e < 4; ++e) {
        vals[e*5+0] = s_t[e];  vals[e*5+1] = s_a[e];
        vals[e*5+2] = s_t2[e]; vals[e*5+3] = s_a2[e];
        vals[e*5+4] = s_c[e];
    }
    #pragma unroll
    for (int v = 0; v < 20; ++v) {
        vals[v] += __shfl_xor(vals[v], 16);
        vals[v] += __shfl_xor(vals[v], 32);
    }
    __shared__ float sred[4][16][20];
    if (lane < 16) {
        #pragma unroll
        for (int v = 0; v < 20; ++v) sred[wave][lane][v] = vals[v];
    }
    __syncthreads();

    if (threadIdx.x == 0) {
        atomicAdd(&rep[0], ssc[0][0] + ssc[1][0] + ssc[2][0] + ssc[3][0]);
        atomicAdd(&rep[1], ssc[0][1] + ssc[1][1] + ssc[2][1] + ssc[3][1]);
    }
    for (int i = threadIdx.x; i < 320; i += THREADS) {
        const int g = i / 20, v = i % 20;
        const float s = sred[0][g][v] + sred[1][g][v] + sred[2][g][v] + sred[3][g][v];
        const int e = v / 5, st = v % 5;
        atomicAdd(&rep[2 + st * 64 + (g * 4 + e)], s);
    }
}

// Collapse 64 replicas per value. 81 blocks x 256: wave w of block b handles
// value j = b*4 + w; lane = replica. 81*4 = 324 exactly.
__global__ __launch_bounds__(256) void vde_collapse(
    const float* __restrict__ ws, float* __restrict__ sums)
{
    const int lane = threadIdx.x & 63;
    const int j = blockIdx.x * 4 + (threadIdx.x >> 6);
    float v = ws[lane * NVAL + j];
    #pragma unroll
    for (int m = 32; m >= 1; m >>= 1) v += __shfl_xor(v, m);
    if (lane == 0) sums[j] = v;
}

__global__ __launch_bounds__(64) void vde_finalize(
    const float* __restrict__ sums, float* __restrict__ out)
{
    const int j = threadIdx.x;              // column 0..63
    const float Nf = (float)N_ROWS;

    const float sum_t  = sums[2 + 0*64 + j];
    const float sum_a  = sums[2 + 1*64 + j];
    const float sum_t2 = sums[2 + 2*64 + j];
    const float sum_a2 = sums[2 + 3*64 + j];
    const float sum_c  = sums[2 + 4*64 + j];

    const float mu_t = sum_t / Nf, mu_a = sum_a / Nf;
    float diag = sum_c - Nf * mu_t * mu_a;
    const float var_t = (sum_t2 - Nf * mu_t * mu_t) / (Nf - 1.f);
    const float var_a = (sum_a2 - Nf * mu_a * mu_a) / (Nf - 1.f);
    float sp = sqrtf(var_t) * sqrtf(var_a);

    #pragma unroll
    for (int m = 32; m >= 1; m >>= 1) {
        diag += __shfl_xor(diag, m);
        sp   += __shfl_xor(sp, m);
    }
    if (j == 0) {
        const float recon_f = sums[0] / (Nf * 128.f);
        const float kl_f    = -0.5f * sums[1] / Nf;
        out[0] = recon_f + kl_f - (diag / Nf) / sp;
    }
}

extern "C" void kernel_launch(void* const* d_in, const int* in_sizes, int n_in,
                              void* d_out, int out_size, void* d_ws, size_t ws_size,
                              hipStream_t stream) {
    const float4* target = (const float4*)d_in[0];
    const float4* output = (const float4*)d_in[1];
    const float4* mean   = (const float4*)d_in[2];
    const float4* logvar = (const float4*)d_in[3];
    const float4* zt     = (const float4*)d_in[4];
    const float4* ztau   = (const float4*)d_in[5];
    float* ws  = (float*)d_ws;
    float* out = (float*)d_out;

    // zero the replicated accumulators (ws re-poisoned to 0xAA each call)
    hipMemsetAsync(ws, 0, NREP * NVAL * sizeof(float), stream);
    vde_main<<<BLOCKS, THREADS, 0, stream>>>(target, output, mean, logvar, zt, ztau, ws);
    vde_collapse<<<81, 256, 0, stream>>>(ws, ws + NREP * NVAL);
    vde_finalize<<<1, 64, 0, stream>>>(ws + NREP * NVAL, out);
}

// Round 4
// 158.380 us; speedup vs baseline: 2.9993x; 1.0135x over previous
//
#include <hip/hip_runtime.h>

// N=65536, D_OUT=128, D_LAT=64, D_Z=64. Streaming multi-reduction.
// R3 lesson: 6 interleaved streams per block cap effective BW at ~3 TB/s.
// R4: block-specialized phases -> each block streams 2 contiguous 32KB chunks.
constexpr int N_ROWS  = 65536;
constexpr int THREADS = 256;
constexpr int B_MSE = 1024, B_KL = 512, B_Z = 512;
constexpr int BLOCKS = B_MSE + B_KL + B_Z;      // 2048
constexpr int F4_BLK = 2048;                    // float4s per block per array
constexpr int IT     = F4_BLK / THREADS;        // 8 iters/thread

constexpr int NVAL = 324;   // [0]=recon, [1]=kl, [2+st*64+col] (5*64)
constexpr int NREP = 64;    // replicas: contention <= 1024/64 = 16 per address

// ws layout (floats): [r*NVAL + v], r in [0,64). memset to 0 each call.

__global__ __launch_bounds__(THREADS) void vde_main(
    const float4* __restrict__ target,
    const float4* __restrict__ output,
    const float4* __restrict__ mean,
    const float4* __restrict__ logvar,
    const float4* __restrict__ zt,
    const float4* __restrict__ ztau,
    float* __restrict__ ws)
{
    const int lane = threadIdx.x & 63;
    const int wave = threadIdx.x >> 6;
    float* rep = ws + (blockIdx.x & (NREP - 1)) * NVAL;

    __shared__ float ssc[4];                 // scalar cross-wave (MSE/KL)
    __shared__ float sred[4][16][20];        // column stats cross-wave (Z)

    if (blockIdx.x < B_MSE) {
        // ---------------- MSE: sum (o - t)^2 over a 32KB chunk of each ----
        const int base = blockIdx.x * F4_BLK + threadIdx.x;
        float recon = 0.f;
        #pragma unroll
        for (int it = 0; it < IT; ++it) {
            float4 o = output[base + it * THREADS];
            float4 t = target[base + it * THREADS];
            float dx = o.x - t.x, dy = o.y - t.y;
            float dz = o.z - t.z, dw = o.w - t.w;
            recon += dx * dx + dy * dy + dz * dz + dw * dw;
        }
        #pragma unroll
        for (int m = 32; m >= 1; m >>= 1) recon += __shfl_xor(recon, m);
        if (lane == 0) ssc[wave] = recon;
        __syncthreads();
        if (threadIdx.x == 0)
            atomicAdd(&rep[0], ssc[0] + ssc[1] + ssc[2] + ssc[3]);

    } else if (blockIdx.x < B_MSE + B_KL) {
        // ---------------- KL: sum (lv - e^lv - m^2 + 1) -------------------
        const int base = (blockIdx.x - B_MSE) * F4_BLK + threadIdx.x;
        float kls = 0.f;
        #pragma unroll
        for (int it = 0; it < IT; ++it) {
            float4 lv = logvar[base + it * THREADS];
            float4 m  = mean[base + it * THREADS];
            kls += (lv.x - __expf(lv.x) - m.x * m.x + 1.f)
                 + (lv.y - __expf(lv.y) - m.y * m.y + 1.f)
                 + (lv.z - __expf(lv.z) - m.z * m.z + 1.f)
                 + (lv.w - __expf(lv.w) - m.w * m.w + 1.f);
        }
        #pragma unroll
        for (int m = 32; m >= 1; m >>= 1) kls += __shfl_xor(kls, m);
        if (lane == 0) ssc[wave] = kls;
        __syncthreads();
        if (threadIdx.x == 0)
            atomicAdd(&rep[1], ssc[0] + ssc[1] + ssc[2] + ssc[3]);

    } else {
        // ---------------- Z column stats ----------------------------------
        // float4 index f = zb*2048 + it*256 + tid -> f%16 == tid%16, so each
        // thread owns fixed 4-column group g = tid&15 (cols 4g..4g+3).
        const int base = (blockIdx.x - B_MSE - B_KL) * F4_BLK + threadIdx.x;
        float s_t[4] = {0,0,0,0}, s_t2[4] = {0,0,0,0};
        float s_a[4] = {0,0,0,0}, s_a2[4] = {0,0,0,0}, s_c[4] = {0,0,0,0};
        #pragma unroll
        for (int it = 0; it < IT; ++it) {
            float4 a = zt[base + it * THREADS];
            float4 b = ztau[base + it * THREADS];
            const float ax[4] = {a.x, a.y, a.z, a.w};
            const float bx[4] = {b.x, b.y, b.z, b.w};
            #pragma unroll
            for (int e = 0; e < 4; ++e) {
                s_t[e]  += ax[e];        s_a[e]  += bx[e];
                s_t2[e] += ax[e]*ax[e];  s_a2[e] += bx[e]*bx[e];
                s_c[e]  += ax[e]*bx[e];
            }
        }
        float vals[20];
        #pragma unroll
        for (int e = 0; e < 4; ++e) {
            vals[e*5+0] = s_t[e];  vals[e*5+1] = s_a[e];
            vals[e*5+2] = s_t2[e]; vals[e*5+3] = s_a2[e];
            vals[e*5+4] = s_c[e];
        }
        #pragma unroll
        for (int v = 0; v < 20; ++v) {
            vals[v] += __shfl_xor(vals[v], 16);
            vals[v] += __shfl_xor(vals[v], 32);
        }
        if (lane < 16) {
            #pragma unroll
            for (int v = 0; v < 20; ++v) sred[wave][lane][v] = vals[v];
        }
        __syncthreads();
        for (int i = threadIdx.x; i < 320; i += THREADS) {
            const int g = i / 20, v = i % 20;
            const float s = sred[0][g][v] + sred[1][g][v]
                          + sred[2][g][v] + sred[3][g][v];
            const int e = v / 5, st = v % 5;
            atomicAdd(&rep[2 + st * 64 + (g * 4 + e)], s);
        }
    }
}

// Collapse 64 replicas + finalize, one block.
__global__ __launch_bounds__(256) void vde_tail(
    const float* __restrict__ ws, float* __restrict__ out)
{
    __shared__ float sums[NVAL];
    for (int j = threadIdx.x; j < NVAL; j += 256) {
        float s = 0.f;
        #pragma unroll
        for (int r = 0; r < NREP; ++r) s += ws[r * NVAL + j];
        sums[j] = s;
    }
    __syncthreads();

    if (threadIdx.x < 64) {
        const int j = threadIdx.x;          // column 0..63
        const float Nf = (float)N_ROWS;
        const float sum_t  = sums[2 + 0*64 + j];
        const float sum_a  = sums[2 + 1*64 + j];
        const float sum_t2 = sums[2 + 2*64 + j];
        const float sum_a2 = sums[2 + 3*64 + j];
        const float sum_c  = sums[2 + 4*64 + j];

        const float mu_t = sum_t / Nf, mu_a = sum_a / Nf;
        float diag = sum_c - Nf * mu_t * mu_a;
        const float var_t = (sum_t2 - Nf * mu_t * mu_t) / (Nf - 1.f);
        const float var_a = (sum_a2 - Nf * mu_a * mu_a) / (Nf - 1.f);
        float sp = sqrtf(var_t) * sqrtf(var_a);

        #pragma unroll
        for (int m = 32; m >= 1; m >>= 1) {
            diag += __shfl_xor(diag, m);
            sp   += __shfl_xor(sp, m);
        }
        if (j == 0) {
            const float recon_f = sums[0] / (Nf * 128.f);
            const float kl_f    = -0.5f * sums[1] / Nf;
            out[0] = recon_f + kl_f - (diag / Nf) / sp;
        }
    }
}

extern "C" void kernel_launch(void* const* d_in, const int* in_sizes, int n_in,
                              void* d_out, int out_size, void* d_ws, size_t ws_size,
                              hipStream_t stream) {
    const float4* target = (const float4*)d_in[0];
    const float4* output = (const float4*)d_in[1];
    const float4* mean   = (const float4*)d_in[2];
    const float4* logvar = (const float4*)d_in[3];
    const float4* zt     = (const float4*)d_in[4];
    const float4* ztau   = (const float4*)d_in[5];
    float* ws  = (float*)d_ws;
    float* out = (float*)d_out;

    // zero the replicated accumulators (ws re-poisoned to 0xAA each call)
    hipMemsetAsync(ws, 0, NREP * NVAL * sizeof(float), stream);
    vde_main<<<BLOCKS, THREADS, 0, stream>>>(target, output, mean, logvar, zt, ztau, ws);
    vde_tail<<<1, 256, 0, stream>>>(ws, out);
}

// Round 5
// 147.981 us; speedup vs baseline: 3.2101x; 1.0703x over previous
//
#include <hip/hip_runtime.h>

// N=65536, D_OUT=128, D_LAT=64, D_Z=64. Streaming multi-reduction.
// R3/R4 lesson: two different access structures both plateau at ~3.1 TB/s
// combined service rate; half the traffic is L2 hits (restore-dirtied lines).
// R5 probe: nontemporal (nt) loads to stream past L2 allocation.
constexpr int N_ROWS  = 65536;
constexpr int THREADS = 256;
constexpr int B_MSE = 1024, B_KL = 512, B_Z = 512;
constexpr int BLOCKS = B_MSE + B_KL + B_Z;      // 2048
constexpr int F4_BLK = 2048;                    // float4s per block per array
constexpr int IT     = F4_BLK / THREADS;        // 8 iters/thread

constexpr int NVAL = 324;   // [0]=recon, [1]=kl, [2+st*64+col] (5*64)
constexpr int NREP = 64;    // replicas: contention <= 16 per address

typedef float f4v __attribute__((ext_vector_type(4)));

__device__ __forceinline__ f4v ntload(const f4v* p) {
    return __builtin_nontemporal_load(p);
}

// ws layout (floats): [r*NVAL + v], r in [0,64). memset to 0 each call.

__global__ __launch_bounds__(THREADS) void vde_main(
    const f4v* __restrict__ target,
    const f4v* __restrict__ output,
    const f4v* __restrict__ mean,
    const f4v* __restrict__ logvar,
    const f4v* __restrict__ zt,
    const f4v* __restrict__ ztau,
    float* __restrict__ ws)
{
    const int lane = threadIdx.x & 63;
    const int wave = threadIdx.x >> 6;
    float* rep = ws + (blockIdx.x & (NREP - 1)) * NVAL;

    __shared__ float ssc[4];                 // scalar cross-wave (MSE/KL)
    __shared__ float sred[4][16][20];        // column stats cross-wave (Z)

    if (blockIdx.x < B_MSE) {
        // ---------------- MSE: sum (o - t)^2 ------------------------------
        const int base = blockIdx.x * F4_BLK + threadIdx.x;
        float recon = 0.f;
        #pragma unroll
        for (int it = 0; it < IT; ++it) {
            f4v o = ntload(&output[base + it * THREADS]);
            f4v t = ntload(&target[base + it * THREADS]);
            f4v d = o - t;
            recon += d[0]*d[0] + d[1]*d[1] + d[2]*d[2] + d[3]*d[3];
        }
        #pragma unroll
        for (int m = 32; m >= 1; m >>= 1) recon += __shfl_xor(recon, m);
        if (lane == 0) ssc[wave] = recon;
        __syncthreads();
        if (threadIdx.x == 0)
            atomicAdd(&rep[0], ssc[0] + ssc[1] + ssc[2] + ssc[3]);

    } else if (blockIdx.x < B_MSE + B_KL) {
        // ---------------- KL: sum (lv - e^lv - m^2 + 1) -------------------
        const int base = (blockIdx.x - B_MSE) * F4_BLK + threadIdx.x;
        float kls = 0.f;
        #pragma unroll
        for (int it = 0; it < IT; ++it) {
            f4v lv = ntload(&logvar[base + it * THREADS]);
            f4v m  = ntload(&mean[base + it * THREADS]);
            kls += (lv[0] - __expf(lv[0]) - m[0]*m[0] + 1.f)
                 + (lv[1] - __expf(lv[1]) - m[1]*m[1] + 1.f)
                 + (lv[2] - __expf(lv[2]) - m[2]*m[2] + 1.f)
                 + (lv[3] - __expf(lv[3]) - m[3]*m[3] + 1.f);
        }
        #pragma unroll
        for (int m = 32; m >= 1; m >>= 1) kls += __shfl_xor(kls, m);
        if (lane == 0) ssc[wave] = kls;
        __syncthreads();
        if (threadIdx.x == 0)
            atomicAdd(&rep[1], ssc[0] + ssc[1] + ssc[2] + ssc[3]);

    } else {
        // ---------------- Z column stats ----------------------------------
        // f = zb*2048 + it*256 + tid -> f%16 == tid%16: each thread owns the
        // fixed 4-column group g = tid&15 (cols 4g..4g+3).
        const int base = (blockIdx.x - B_MSE - B_KL) * F4_BLK + threadIdx.x;
        float s_t[4] = {0,0,0,0}, s_t2[4] = {0,0,0,0};
        float s_a[4] = {0,0,0,0}, s_a2[4] = {0,0,0,0}, s_c[4] = {0,0,0,0};
        #pragma unroll
        for (int it = 0; it < IT; ++it) {
            f4v a = ntload(&zt[base + it * THREADS]);
            f4v b = ntload(&ztau[base + it * THREADS]);
            #pragma unroll
            for (int e = 0; e < 4; ++e) {
                s_t[e]  += a[e];       s_a[e]  += b[e];
                s_t2[e] += a[e]*a[e];  s_a2[e] += b[e]*b[e];
                s_c[e]  += a[e]*b[e];
            }
        }
        float vals[20];
        #pragma unroll
        for (int e = 0; e < 4; ++e) {
            vals[e*5+0] = s_t[e];  vals[e*5+1] = s_a[e];
            vals[e*5+2] = s_t2[e]; vals[e*5+3] = s_a2[e];
            vals[e*5+4] = s_c[e];
        }
        #pragma unroll
        for (int v = 0; v < 20; ++v) {
            vals[v] += __shfl_xor(vals[v], 16);
            vals[v] += __shfl_xor(vals[v], 32);
        }
        if (lane < 16) {
            #pragma unroll
            for (int v = 0; v < 20; ++v) sred[wave][lane][v] = vals[v];
        }
        __syncthreads();
        for (int i = threadIdx.x; i < 320; i += THREADS) {
            const int g = i / 20, v = i % 20;
            const float s = sred[0][g][v] + sred[1][g][v]
                          + sred[2][g][v] + sred[3][g][v];
            const int e = v / 5, st = v % 5;
            atomicAdd(&rep[2 + st * 64 + (g * 4 + e)], s);
        }
    }
}

// Collapse 64 replicas + finalize, one block.
__global__ __launch_bounds__(256) void vde_tail(
    const float* __restrict__ ws, float* __restrict__ out)
{
    __shared__ float sums[NVAL];
    for (int j = threadIdx.x; j < NVAL; j += 256) {
        float s = 0.f;
        #pragma unroll
        for (int r = 0; r < NREP; ++r) s += ws[r * NVAL + j];
        sums[j] = s;
    }
    __syncthreads();

    if (threadIdx.x < 64) {
        const int j = threadIdx.x;          // column 0..63
        const float Nf = (float)N_ROWS;
        const float sum_t  = sums[2 + 0*64 + j];
        const float sum_a  = sums[2 + 1*64 + j];
        const float sum_t2 = sums[2 + 2*64 + j];
        const float sum_a2 = sums[2 + 3*64 + j];
        const float sum_c  = sums[2 + 4*64 + j];

        const float mu_t = sum_t / Nf, mu_a = sum_a / Nf;
        float diag = sum_c - Nf * mu_t * mu_a;
        const float var_t = (sum_t2 - Nf * mu_t * mu_t) / (Nf - 1.f);
        const float var_a = (sum_a2 - Nf * mu_a * mu_a) / (Nf - 1.f);
        float sp = sqrtf(var_t) * sqrtf(var_a);

        #pragma unroll
        for (int m = 32; m >= 1; m >>= 1) {
            diag += __shfl_xor(diag, m);
            sp   += __shfl_xor(sp, m);
        }
        if (j == 0) {
            const float recon_f = sums[0] / (Nf * 128.f);
            const float kl_f    = -0.5f * sums[1] / Nf;
            out[0] = recon_f + kl_f - (diag / Nf) / sp;
        }
    }
}

extern "C" void kernel_launch(void* const* d_in, const int* in_sizes, int n_in,
                              void* d_out, int out_size, void* d_ws, size_t ws_size,
                              hipStream_t stream) {
    const f4v* target = (const f4v*)d_in[0];
    const f4v* output = (const f4v*)d_in[1];
    const f4v* mean   = (const f4v*)d_in[2];
    const f4v* logvar = (const f4v*)d_in[3];
    const f4v* zt     = (const f4v*)d_in[4];
    const f4v* ztau   = (const f4v*)d_in[5];
    float* ws  = (float*)d_ws;
    float* out = (float*)d_out;

    // zero the replicated accumulators (ws re-poisoned to 0xAA each call)
    hipMemsetAsync(ws, 0, NREP * NVAL * sizeof(float), stream);
    vde_main<<<BLOCKS, THREADS, 0, stream>>>(target, output, mean, logvar, zt, ztau, ws);
    vde_tail<<<1, 256, 0, stream>>>(ws, out);
}